// Round 11
// baseline (608.451 us; speedup 1.0000x reference)
//
#include <hip/hip_runtime.h>

#define NB 32
#define NS 2048
#define ND 1024

typedef unsigned short u16;
typedef unsigned int u32;
typedef __attribute__((ext_vector_type(8))) short bf16x8;
typedef __attribute__((ext_vector_type(4))) float f32x4;

__device__ __forceinline__ u16 f2bf(float f) {
    u32 u = __float_as_uint(f);
    u32 r = u + 0x7fffu + ((u >> 16) & 1u);
    return (u16)(r >> 16);
}

// ---------------- kernel 1: per-tile masked column sums -> partial[c][b][d] (no atomics)
// + bf16 A-fragment-packed stash (layout unchanged from r9, HW-validated)
template <bool DO_STASH>
__global__ void k_prep(const float* __restrict__ X, const int* __restrict__ len,
                       float* __restrict__ partial, u16* __restrict__ stash) {
    int b = blockIdx.x >> 5, c = blockIdx.x & 31;
    int L = len[b];
    int s0 = c * 64;
    if (s0 >= L) return;                    // dead tiles: partial stays memset-0
    int n = min(64, L - s0);
    int t = threadIdx.x;
    const float4* base = (const float4*)(X + (size_t)b * NS * ND + (size_t)s0 * ND) + t;
    u16* tb = stash + ((size_t)blockIdx.x << 16)
            + (size_t)(t >> 3) * 2048 + (((t >> 1) & 3) << 7) + ((t & 1) << 2);
    float4 acc = {0.f, 0.f, 0.f, 0.f};
    for (int i = 0; i < n; ++i) {
        float4 x = base[i * (ND / 4)];
        acc.x += x.x; acc.y += x.y; acc.z += x.z; acc.w += x.w;
        if constexpr (DO_STASH) {
            u32 lo = (u32)f2bf(x.x) | ((u32)f2bf(x.y) << 16);
            u32 hi = (u32)f2bf(x.z) | ((u32)f2bf(x.w) << 16);
            *(uint2*)(tb + (i >> 4) * 512 + (i & 15) * 8) = make_uint2(lo, hi);
        }
    }
    if constexpr (DO_STASH) {
        for (int i = n; i < 64; ++i)
            *(uint2*)(tb + (i >> 4) * 512 + (i & 15) * 8) = make_uint2(0u, 0u);
    }
    *(float4*)(partial + ((size_t)(c * NB + b)) * ND + t * 4) = acc;
}

// ---------------- kernel 2: sumX[b,d] = sum_c partial[c][b][d]   (grid 128 = 32 b x 4 dq)
__global__ void k_reduce(const float* __restrict__ partial, float* __restrict__ sumX) {
    int b = blockIdx.x >> 2, dq = blockIdx.x & 3;
    int d = dq * 256 + threadIdx.x;
    float s = 0.f;
    #pragma unroll
    for (int c = 0; c < 32; ++c) s += partial[((size_t)(c * NB + b)) * ND + d];
    sumX[b * ND + d] = s;
}

// ---------------- kernel 3: pack Wl -> bf16 B-fragments via LDS tile (coalesced both sides)
// frag fg = nc*128 + kk*4 + j holds B[k=kk*32+(l>>4)*8+e][n=nc*64+j*16+(l&15)] (r9 layout)
__global__ void k_pack(const float* __restrict__ Wl, u16* __restrict__ pack) {
    __shared__ float tile[64][65];
    int t = threadIdx.x;
    int kt = blockIdx.x >> 4, nt = blockIdx.x & 15;
    int k0 = kt * 64, n0 = nt * 64;
    #pragma unroll
    for (int rep = 0; rep < 4; ++rep) {
        int idx4 = t + rep * 256;           // float4 units, 16 per row
        int r = idx4 >> 4, c4 = idx4 & 15;
        float4 w4 = *(const float4*)(Wl + (size_t)(k0 + r) * ND + n0 + c4 * 4);
        tile[r][c4 * 4 + 0] = w4.x; tile[r][c4 * 4 + 1] = w4.y;
        tile[r][c4 * 4 + 2] = w4.z; tile[r][c4 * 4 + 3] = w4.w;
    }
    __syncthreads();
    u32* p32 = (u32*)pack;
    int l = t >> 2, epair = (t & 3) * 2;    // u32 #t of each frag: lane l, elems epair,epair+1
    #pragma unroll
    for (int f = 0; f < 8; ++f) {
        int kk2 = f >> 2, j = f & 3;
        int kloc = kk2 * 32 + (l >> 4) * 8 + epair;
        int nloc = j * 16 + (l & 15);
        u32 v = (u32)f2bf(tile[kloc][nloc]) | ((u32)f2bf(tile[kloc + 1][nloc]) << 16);
        int fg = nt * 128 + (kt * 2 + kk2) * 4 + j;
        p32[(size_t)fg * 256 + t] = v;
    }
}

// ---------------- kernel 4: ygp[db][b][e] = partial gproj over d-block (grid 128, no atomics)
__global__ void k_gproj(const float* __restrict__ sumX, const float* __restrict__ Wg,
                        float* __restrict__ ygp) {
    __shared__ float sx[32][64];
    int t = threadIdx.x;
    int eb = blockIdx.x & 15, db = blockIdx.x >> 4;
    int e = eb * 64 + (t & 63);
    int bg = t >> 6;
    float acc[8] = {0.f,0.f,0.f,0.f,0.f,0.f,0.f,0.f};
    for (int d0 = db * 128; d0 < db * 128 + 128; d0 += 64) {
        __syncthreads();
        #pragma unroll
        for (int j = 0; j < 8; ++j) {
            int idx = t + j * 256;
            sx[idx >> 6][idx & 63] = sumX[(idx >> 6) * ND + d0 + (idx & 63)];
        }
        __syncthreads();
        for (int dd = 0; dd < 64; ++dd) {
            float wv = Wg[(size_t)(d0 + dd) * ND + e];
            #pragma unroll
            for (int j = 0; j < 8; ++j) acc[j] += wv * sx[bg * 8 + j][dd];
        }
    }
    #pragma unroll
    for (int j = 0; j < 8; ++j)
        ygp[((size_t)(db * NB) + bg * 8 + j) * ND + e] = acc[j];
}

// ---------------- kernel 5: gp[b,:] = l2norm(sum_db ygp[db][b,:])
__global__ void k_gnorm(const float* __restrict__ ygp, float* __restrict__ gp) {
    int b = blockIdx.x, t = threadIdx.x;
    float4 y = {0.f, 0.f, 0.f, 0.f};
    #pragma unroll
    for (int db = 0; db < 8; ++db) {
        float4 p = ((const float4*)(ygp + (size_t)(db * NB + b) * ND))[t];
        y.x += p.x; y.y += p.y; y.z += p.z; y.w += p.w;
    }
    float ss = y.x * y.x + y.y * y.y + y.z * y.z + y.w * y.w;
    #pragma unroll
    for (int o = 32; o; o >>= 1) ss += __shfl_down(ss, o);
    __shared__ float wsum[4];
    if ((t & 63) == 0) wsum[t >> 6] = ss;
    __syncthreads();
    float tot = wsum[0] + wsum[1] + wsum[2] + wsum[3];
    float sc = 1.f / sqrtf(fmaxf(tot, 1e-12f));
    float4 g = {y.x * sc, y.y * sc, y.z * sc, y.w * sc};
    ((float4*)(gp + (size_t)b * ND))[t] = g;
}

// ---------------- kernel 6: MFMA phase, K-split x2 (grid 2048 = 32 b x 32 tile x 2 kh)
// writes per-K-half partials norm2p/dotp[kh][(b*32+tile)*64 + row]
template <bool STASH>
__global__ __launch_bounds__(256, 3) void k_mfma(
    const float* __restrict__ X, const int* __restrict__ len,
    const u16* __restrict__ stash, const u16* __restrict__ pack,
    const float* __restrict__ gp, float* __restrict__ norm2p, float* __restrict__ dotp) {
    __shared__ float gp_s[1024];
    __shared__ float norm2_s[4][64];
    __shared__ float dot_s[4][64];

    int b = blockIdx.x >> 6;
    int tile = (blockIdx.x >> 1) & 31;
    int kh = blockIdx.x & 1;
    int L = len[b];
    int s0 = tile * 64;
    if (s0 >= L) return;
    int valid = min(64, L - s0);
    int t = threadIdx.x;
    int lane = t & 63, w = t >> 6;
    int kh16 = kh * 16;

    for (int jj = t; jj < 1024; jj += 256) gp_s[jj] = gp[b * ND + jj];
    ((float*)norm2_s)[t] = 0.f;
    ((float*)dot_s)[t] = 0.f;
    __syncthreads();

    const u16* ta = stash + ((size_t)(b * 32 + tile) << 16) + lane * 8;
    const float* Xb = X + (size_t)b * NS * ND + (size_t)s0 * ND;

    for (int q = 0; q < 4; ++q) {
        int nc = w + q * 4;
        const u16* pb = pack + (size_t)nc * 65536 + lane * 8;
        f32x4 acc[4][4];
        #pragma unroll
        for (int rb = 0; rb < 4; ++rb)
            #pragma unroll
            for (int j = 0; j < 4; ++j) acc[rb][j] = (f32x4){0.f, 0.f, 0.f, 0.f};

        #pragma unroll 2
        for (int kk = kh16; kk < kh16 + 16; ++kk) {
            bf16x8 a[4], bb[4];
            if constexpr (STASH) {
                #pragma unroll
                for (int rb = 0; rb < 4; ++rb)
                    a[rb] = *(const bf16x8*)(ta + (kk * 4 + rb) * 512);
            } else {
                int kb = kk * 32 + ((lane >> 4) << 3);
                #pragma unroll
                for (int rb = 0; rb < 4; ++rb) {
                    int row = (rb << 4) + (lane & 15);
                    bf16x8 av = {0,0,0,0,0,0,0,0};
                    if (row < valid) {
                        float4 x0 = *(const float4*)(Xb + (size_t)row * ND + kb);
                        float4 x1 = *(const float4*)(Xb + (size_t)row * ND + kb + 4);
                        av[0] = (short)f2bf(x0.x); av[1] = (short)f2bf(x0.y);
                        av[2] = (short)f2bf(x0.z); av[3] = (short)f2bf(x0.w);
                        av[4] = (short)f2bf(x1.x); av[5] = (short)f2bf(x1.y);
                        av[6] = (short)f2bf(x1.z); av[7] = (short)f2bf(x1.w);
                    }
                    a[rb] = av;
                }
            }
            #pragma unroll
            for (int j = 0; j < 4; ++j)
                bb[j] = *(const bf16x8*)(pb + (kk * 4 + j) * 512);
            #pragma unroll
            for (int j = 0; j < 4; ++j)
                #pragma unroll
                for (int rb = 0; rb < 4; ++rb)
                    acc[rb][j] = __builtin_amdgcn_mfma_f32_16x16x32_bf16(a[rb], bb[j], acc[rb][j], 0, 0, 0);
        }
        // C layout: col n-local = lane&15, row = rb*16 + (lane>>4)*4 + reg
        float gpv[4];
        #pragma unroll
        for (int j = 0; j < 4; ++j) gpv[j] = gp_s[nc * 64 + j * 16 + (lane & 15)];
        #pragma unroll
        for (int rb = 0; rb < 4; ++rb) {
            #pragma unroll
            for (int reg = 0; reg < 4; ++reg) {
                float s = 0.f, d = 0.f;
                #pragma unroll
                for (int j = 0; j < 4; ++j) {
                    float y = acc[rb][j][reg];
                    s += y * y;
                    d += y * gpv[j];
                }
                s += __shfl_xor(s, 1); d += __shfl_xor(d, 1);
                s += __shfl_xor(s, 2); d += __shfl_xor(d, 2);
                s += __shfl_xor(s, 4); d += __shfl_xor(d, 4);
                s += __shfl_xor(s, 8); d += __shfl_xor(d, 8);
                if ((lane & 15) == 0) {
                    int row = (rb << 4) + ((lane >> 4) << 2) + reg;
                    norm2_s[w][row] += s;
                    dot_s[w][row] += d;
                }
            }
        }
    }
    __syncthreads();
    if (t < 64) {
        int idx = (b * 32 + tile) * 64 + t;
        norm2p[kh * 65536 + idx] = norm2_s[0][t] + norm2_s[1][t] + norm2_s[2][t] + norm2_s[3][t];
        dotp[kh * 65536 + idx]   = dot_s[0][t] + dot_s[1][t] + dot_s[2][t] + dot_s[3][t];
    }
}

// ---------------- kernel 7: attention + weighted output sum (grid 1024)
__global__ void k_out(const float* __restrict__ X, const int* __restrict__ len,
                      const float* __restrict__ norm2p, const float* __restrict__ dotp,
                      float* __restrict__ out) {
    __shared__ float att_s[64];
    int b = blockIdx.x >> 5, tile = blockIdx.x & 31;
    int L = len[b];
    int s0 = tile * 64;
    if (s0 >= L) return;
    int valid = min(64, L - s0);
    int t = threadIdx.x;
    if (t < 64) {
        int idx = (b * 32 + tile) * 64 + t;
        float n2 = norm2p[idx] + norm2p[65536 + idx];
        float dp = dotp[idx] + dotp[65536 + idx];
        att_s[t] = dp / sqrtf(fmaxf(n2, 1e-12f));
    }
    __syncthreads();
    const float* Xb = X + (size_t)b * NS * ND + (size_t)s0 * ND;
    float4 acc4 = {0.f, 0.f, 0.f, 0.f};
    #pragma unroll 4
    for (int i = 0; i < valid; ++i) {
        float a = att_s[i];
        float4 x = ((const float4*)(Xb + (size_t)i * ND))[t];
        acc4.x += a * x.x; acc4.y += a * x.y; acc4.z += a * x.z; acc4.w += a * x.w;
    }
    float* o = out + b * ND + t * 4;
    atomicAdd(o + 0, acc4.x); atomicAdd(o + 1, acc4.y);
    atomicAdd(o + 2, acc4.z); atomicAdd(o + 3, acc4.w);
}

extern "C" void kernel_launch(void* const* d_in, const int* in_sizes, int n_in,
                              void* d_out, int out_size, void* d_ws, size_t ws_size,
                              hipStream_t stream) {
    (void)in_sizes; (void)n_in; (void)out_size;
    const float* X  = (const float*)d_in[0];
    const int* len  = (const int*)d_in[1];
    const float* Wg = (const float*)d_in[2];
    const float* Wl = (const float*)d_in[3];
    float* out = (float*)d_out;

    char* ws = (char*)d_ws;
    float* partial = (float*)(ws + 0);          // 4 MiB  (32c x 32b x 1024d)
    float* sumX    = (float*)(ws + 4194304);    // 128 KiB
    float* ygp     = (float*)(ws + 4325376);    // 1 MiB  (8db x 32b x 1024e)
    float* gp      = (float*)(ws + 5373952);    // 128 KiB
    u16*   pack    = (u16*)(ws + 5505024);      // 2 MiB
    float* norm2p  = (float*)(ws + 7602176);    // 512 KiB (2kh x 1024 x 64)
    float* dotp    = (float*)(ws + 8126464);    // 512 KiB
    u16*   stash   = (u16*)(ws + 8650752);      // 128 MiB (A-frag tile images)
    const size_t need = 8650752ull + (size_t)NB * 32 * 131072ull;  // 142.9 MB
    int use_stash = ws_size >= need;

    hipMemsetAsync(partial, 0, 4194304, stream);
    hipMemsetAsync(out, 0, NB * ND * sizeof(float), stream);

    if (use_stash)
        k_prep<true> <<<NB * 32, 256, 0, stream>>>(X, len, partial, stash);
    else
        k_prep<false><<<NB * 32, 256, 0, stream>>>(X, len, partial, stash);
    k_reduce<<<128, 256, 0, stream>>>(partial, sumX);
    k_pack  <<<256, 256, 0, stream>>>(Wl, pack);
    k_gproj <<<128, 256, 0, stream>>>(sumX, Wg, ygp);
    k_gnorm <<<NB, 256, 0, stream>>>(ygp, gp);
    if (use_stash)
        k_mfma<true> <<<NB * 32 * 2, 256, 0, stream>>>(X, len, stash, pack, gp, norm2p, dotp);
    else
        k_mfma<false><<<NB * 32 * 2, 256, 0, stream>>>(X, len, stash, pack, gp, norm2p, dotp);
    k_out  <<<NB * 32, 256, 0, stream>>>(X, len, norm2p, dotp, out);
}